// Round 1
// baseline (935.175 us; speedup 1.0000x reference)
//
#include <hip/hip_runtime.h>
#include <math.h>

// Problem constants
// B=8, C=256, H=64, W=64, G=4, K=3, KK=9, Cg=64
// ws layout (float offsets):
//   w_off_t [2304][108]      @ 0        (248832)
//   w_dcn_t [G][576][64]     @ 248832   (147456)
//   off     [B][108][64][64] @ 396288   (3538944)
//   dcn     [B][256][64][64] @ 3935232  (8388608)
// total 12,323,840 floats = 49.3 MB

__global__ __launch_bounds__(256) void k_transpose(
    const float* __restrict__ w_off, const float* __restrict__ w_dcn,
    float* __restrict__ w_off_t, float* __restrict__ w_dcn_t) {
  int i = blockIdx.x * 256 + threadIdx.x;
  const int n1 = 2304 * 108;
  if (i < n1) {
    int co = i % 108, ckk = i / 108;
    w_off_t[i] = w_off[co * 2304 + ckk];
  } else {
    int j = i - n1;
    if (j < 4 * 576 * 64) {
      int co = j & 63;
      int ckk = (j >> 6) % 576;
      int g = j / (576 * 64);
      w_dcn_t[j] = w_dcn[(g * 64 + co) * 576 + ckk];
    }
  }
}

// Offset conv: 3x3 SAME, Cin=256 -> Cout=108. Block=128 threads (thread=cout,
// 108 active), 16 consecutive pixels of one row per block. 2048 blocks.
__global__ __launch_bounds__(128) void k_offconv(
    const float* __restrict__ x, const float* __restrict__ w_off_t,
    const float* __restrict__ b_off, float* __restrict__ off) {
  __shared__ float patch[32 * 3 * 20];  // 32 ch x 3 rows x 18 cols (pad 20)
  int p0 = blockIdx.x * 16;
  int b = p0 >> 12;
  int h = (p0 & 4095) >> 6;
  int w0 = p0 & 63;  // multiple of 16
  int tid = threadIdx.x;
  int co = tid;
  float acc[16];
#pragma unroll
  for (int i = 0; i < 16; ++i) acc[i] = 0.f;

  for (int cb = 0; cb < 256; cb += 32) {
    __syncthreads();
    for (int idx = tid; idx < 32 * 3 * 18; idx += 128) {
      int dx = idx % 18;
      int dy = (idx / 18) % 3;
      int cl = idx / 54;
      int hh = h - 1 + dy, wp = w0 - 1 + dx;
      float v = 0.f;
      if ((unsigned)hh < 64u && (unsigned)wp < 64u)
        v = x[(((b * 256) + cb + cl) * 64 + hh) * 64 + wp];
      patch[(cl * 3 + dy) * 20 + dx] = v;
    }
    __syncthreads();
    if (co < 108) {
      for (int cl = 0; cl < 32; ++cl) {
        const float* pr = &patch[(cl * 3) * 20];
        float r[3][18];
#pragma unroll
        for (int dy = 0; dy < 3; ++dy)
#pragma unroll
          for (int dx = 0; dx < 18; ++dx) r[dy][dx] = pr[dy * 20 + dx];
        int ckk = (cb + cl) * 9;
#pragma unroll
        for (int kk = 0; kk < 9; ++kk) {
          float wv = w_off_t[(ckk + kk) * 108 + co];
          int ky = kk / 3, kx = kk % 3;
#pragma unroll
          for (int px = 0; px < 16; ++px) acc[px] += wv * r[ky][kx + px];
        }
      }
    }
  }
  if (co < 108) {
    float bias = b_off[co];
    float* o = &off[((b * 108 + co) * 64 + h) * 64 + w0];
#pragma unroll
    for (int px = 0; px < 16; ++px) o[px] = acc[px] + bias;
  }
}

// DCN: one block per (b, g, row h). 256 threads. Phase1: sampling params for
// 64 px x 9 taps. Then 8 chunks of 8 input channels: gather sampled[72][64]
// into LDS, then register-blocked matmul (thread = (cout, px-quarter)).
__global__ __launch_bounds__(256) void k_dcn(
    const float* __restrict__ x, const float* __restrict__ off,
    const float* __restrict__ w_dcn_t, const float* __restrict__ b_dcn,
    float* __restrict__ dcn) {
  __shared__ int4 s_idx[576];
  __shared__ float4 s_wgt[576];
  __shared__ float s_smp[72 * 64];

  int bi = blockIdx.x;  // B*G*H = 2048
  int h = bi & 63;
  int g = (bi >> 6) & 3;
  int b = bi >> 8;
  int tid = threadIdx.x;

  // phase 1: sampling params, item = kk*64 + w
  const float* offb = off + (size_t)b * 108 * 4096;
  for (int it = tid; it < 576; it += 256) {
    int kk = it >> 6;
    int w = it & 63;
    int sp = h * 64 + w;
    float oy = offb[((g * 9 + kk) * 2 + 0) * 4096 + sp];
    float ox = offb[((g * 9 + kk) * 2 + 1) * 4096 + sp];
    float mz = offb[(72 + g * 9 + kk) * 4096 + sp];
    float m = 1.f / (1.f + __expf(-mz));
    float py = (float)h + (float)(kk / 3 - 1) + oy;
    float pxf = (float)w + (float)(kk % 3 - 1) + ox;
    float y0 = floorf(py), x0 = floorf(pxf);
    float wy1 = py - y0, wy0 = 1.f - wy1;
    float wx1 = pxf - x0, wx0 = 1.f - wx1;
    int y0i = (int)y0, x0i = (int)x0;
    int y1i = y0i + 1, x1i = x0i + 1;
    bool vy0 = (y0i >= 0) & (y0i < 64), vy1 = (y1i >= 0) & (y1i < 64);
    bool vx0 = (x0i >= 0) & (x0i < 64), vx1 = (x1i >= 0) & (x1i < 64);
    int cy0 = min(max(y0i, 0), 63), cy1 = min(max(y1i, 0), 63);
    int cx0 = min(max(x0i, 0), 63), cx1 = min(max(x1i, 0), 63);
    s_idx[it] = make_int4(cy0 * 64 + cx0, cy0 * 64 + cx1,
                          cy1 * 64 + cx0, cy1 * 64 + cx1);
    s_wgt[it] = make_float4((vy0 && vx0) ? wy0 * wx0 * m : 0.f,
                            (vy0 && vx1) ? wy0 * wx1 * m : 0.f,
                            (vy1 && vx0) ? wy1 * wx0 * m : 0.f,
                            (vy1 && vx1) ? wy1 * wx1 * m : 0.f);
  }
  __syncthreads();

  int px = tid & 63, iq = tid >> 6;  // gather mapping
  int co = tid & 63, q = tid >> 6;   // matmul mapping
  float acc[16];
#pragma unroll
  for (int i = 0; i < 16; ++i) acc[i] = 0.f;

  for (int ch = 0; ch < 8; ++ch) {
    // gather sampled[72][64] for channels ch*8 .. ch*8+7
    const float* xb = x + ((size_t)(b * 256 + g * 64 + ch * 8)) * 4096;
#pragma unroll 3
    for (int j = 0; j < 18; ++j) {
      int ckk_l = iq + 4 * j;  // 0..71
      int cl = ckk_l / 9, kk = ckk_l % 9;
      int it = kk * 64 + px;
      int4 id = s_idx[it];
      float4 wt = s_wgt[it];
      const float* xp = xb + cl * 4096;
      float v = wt.x * xp[id.x] + wt.y * xp[id.y] + wt.z * xp[id.z] +
                wt.w * xp[id.w];
      s_smp[ckk_l * 64 + px] = v;
    }
    __syncthreads();
    // matmul partial: acc[px'] += w[ckk][co] * smp[ckk][q*16+px']
    const float* wt = w_dcn_t + (g * 576 + ch * 72) * 64;
    for (int k = 0; k < 72; ++k) {
      float wv = wt[k * 64 + co];
      const float4* sp = (const float4*)&s_smp[k * 64 + q * 16];
#pragma unroll
      for (int i = 0; i < 4; ++i) {
        float4 sv = sp[i];
        acc[4 * i + 0] += wv * sv.x;
        acc[4 * i + 1] += wv * sv.y;
        acc[4 * i + 2] += wv * sv.z;
        acc[4 * i + 3] += wv * sv.w;
      }
    }
    __syncthreads();
  }
  float bias = b_dcn[g * 64 + co];
  float* o = dcn + (((size_t)(b * 256 + g * 64 + co)) * 64 + h) * 64 + q * 16;
#pragma unroll
  for (int i = 0; i < 16; ++i) o[i] = acc[i] + bias;
}

// LayerNorm over C + sigmoid + gate. Thread = pixel, coalesced stride-4096
// channel loop, two passes (mean/var via sum & sumsq, then normalize).
__global__ __launch_bounds__(256) void k_ln(
    const float* __restrict__ dcn, const float* __restrict__ x,
    const float* __restrict__ gamma, const float* __restrict__ beta,
    float* __restrict__ out) {
  int p = blockIdx.x * 256 + threadIdx.x;  // 32768 pixels
  int b = p >> 12, hw = p & 4095;
  const float* ob = dcn + (size_t)b * 256 * 4096 + hw;
  const float* xb = x + (size_t)b * 256 * 4096 + hw;
  float* yb = out + (size_t)b * 256 * 4096 + hw;
  float s = 0.f, s2 = 0.f;
  for (int c = 0; c < 256; ++c) {
    float v = ob[c * 4096];
    s += v;
    s2 += v * v;
  }
  float mu = s * (1.f / 256.f);
  float var = s2 * (1.f / 256.f) - mu * mu;
  float rs = rsqrtf(var + 1e-5f);
  for (int c = 0; c < 256; ++c) {
    float v = ob[c * 4096];
    float nrm = (v - mu) * rs * gamma[c] + beta[c];
    float attn = 1.f / (1.f + __expf(-nrm));
    yb[c * 4096] = xb[c * 4096] * attn;
  }
}

extern "C" void kernel_launch(void* const* d_in, const int* in_sizes, int n_in,
                              void* d_out, int out_size, void* d_ws,
                              size_t ws_size, hipStream_t stream) {
  const float* x = (const float*)d_in[0];
  const float* w_off = (const float*)d_in[1];
  const float* b_off = (const float*)d_in[2];
  const float* w_dcn = (const float*)d_in[3];
  const float* b_dcn = (const float*)d_in[4];
  const float* gamma = (const float*)d_in[5];
  const float* beta = (const float*)d_in[6];
  float* out = (float*)d_out;
  float* ws = (float*)d_ws;

  float* w_off_t = ws;              // 248832
  float* w_dcn_t = ws + 248832;     // 147456
  float* offb = ws + 396288;        // 3538944
  float* dcn = ws + 3935232;        // 8388608

  k_transpose<<<(248832 + 147456 + 255) / 256, 256, 0, stream>>>(
      w_off, w_dcn, w_off_t, w_dcn_t);
  k_offconv<<<2048, 128, 0, stream>>>(x, w_off_t, b_off, offb);
  k_dcn<<<2048, 256, 0, stream>>>(x, offb, w_dcn_t, b_dcn, dcn);
  k_ln<<<128, 256, 0, stream>>>(dcn, x, gamma, beta, out);
}

// Round 4
// 868.931 us; speedup vs baseline: 1.0762x; 1.0762x over previous
//
#include <hip/hip_runtime.h>
#include <math.h>

// B=8, C=256, H=W=64, G=4, K=3, KK=9, Cg=64
// BISECTION ROUND: MFMA k_offconv (round-3) + proven VALU k_dcn (round-1).
// ws layout (bytes):
//   offb  fp32 [8][108][64][64]  @ 0          (14,155,776)
//   dcnb  fp32 [8][256][64][64]  @ 14,155,776 (33,554,432)
//     wo_hi short [112][2304]    @ 14,155,776 (516,096)  aliases dcnb start;
//     wo_lo short [112][2304]    @ 14,671,872 (516,096)  consumed by k_offconv
//                                                        before k_dcn writes dcnb
//   w_dcn_t fp32 [4][576][64]    @ 47,710,208 (589,824)
// total 48,300,032 B (< round-1's proven 49,295,360)

typedef __attribute__((ext_vector_type(4))) short s16x4;
typedef __attribute__((ext_vector_type(8))) short s16x8;
typedef __attribute__((ext_vector_type(4))) float f32x4;

union S8 { s16x8 v; s16x4 h[2]; };

__device__ __forceinline__ s16x8 ld8(const short* p) {
  S8 r;
  r.h[0] = *(const s16x4*)p;
  r.h[1] = *(const s16x4*)(p + 4);
  return r.v;
}

__device__ __forceinline__ unsigned short bfr(float v) {  // RNE to bf16
  unsigned u = __float_as_uint(v);
  u = (u + 0x7FFFu + ((u >> 16) & 1u)) >> 16;
  return (unsigned short)u;
}
__device__ __forceinline__ float bff(unsigned short s) {
  return __uint_as_float(((unsigned)s) << 16);
}
__device__ __forceinline__ void split(float v, short& hi, short& lo) {
  unsigned short h = bfr(v);
  hi = (short)h;
  lo = (short)bfr(v - bff(h));  // v - bff(h) exact in fp32
}

__global__ __launch_bounds__(256) void k_prep(
    const float* __restrict__ w_off, const float* __restrict__ w_dcn,
    short* __restrict__ wo_hi, short* __restrict__ wo_lo,
    float* __restrict__ w_dcn_t) {
  int i = blockIdx.x * 256 + threadIdx.x;
  const int n1 = 112 * 2304;
  if (i < n1) {
    int co = i / 2304, k = i % 2304;
    int tap = k >> 8, ch = k & 255;  // k = tap*256 + ch
    float v = (co < 108) ? w_off[(co * 256 + ch) * 9 + tap] : 0.f;
    short h, l;
    split(v, h, l);
    wo_hi[i] = h;
    wo_lo[i] = l;
  } else {
    int j = i - n1;  // exactly 147456 remaining threads
    int co = j & 63;
    int ckk = (j >> 6) % 576;  // ckk = cl*9 + kk (round-1 layout)
    int g = j / 36864;
    w_dcn_t[j] = w_dcn[(g * 64 + co) * 576 + ckk];
  }
}

// Offset conv as bf16-split MFMA GEMM (round-3 verbatim).
// Block=(b,h): out[108][64] = W[108][2304] x P. 36 K-chunks of 64.
__global__ __launch_bounds__(256) void k_offconv(
    const float* __restrict__ x, const short* __restrict__ wo_hi,
    const short* __restrict__ wo_lo, const float* __restrict__ b_off,
    float* __restrict__ off) {
  __shared__ short p_hi[64 * 68];
  __shared__ short p_lo[64 * 68];
  int b = blockIdx.x >> 6, h = blockIdx.x & 63;
  int tid = threadIdx.x;
  int px = tid & 63, iq = tid >> 6;
  int lane = tid & 63, wv = tid >> 6;
  int quad = lane >> 4, l15 = lane & 15;

  f32x4 zero4 = {0.f, 0.f, 0.f, 0.f};
  f32x4 acc[7];
#pragma unroll
  for (int i = 0; i < 7; ++i) acc[i] = zero4;

  const float* xb = x + (size_t)b * 256 * 4096;

  for (int c = 0; c < 36; ++c) {
    int tap = c >> 2, ch0 = (c & 3) << 6;
    int ky = tap / 3, kx = tap % 3;
    int hh = h - 1 + ky;
    int col = px - 1 + kx;
    bool vok = ((unsigned)hh < 64u) & ((unsigned)col < 64u);
    const float* xrow = xb + (size_t)ch0 * 4096 + hh * 64 + col;
#pragma unroll
    for (int j = 0; j < 4; ++j) {
      int cl0 = 4 * iq + 16 * j;
      s16x4 ph, pl;
#pragma unroll
      for (int m = 0; m < 4; ++m) {
        float v = vok ? xrow[(size_t)(cl0 + m) * 4096] : 0.f;
        short hv, lv;
        split(v, hv, lv);
        ph[m] = hv;
        pl[m] = lv;
      }
      *(s16x4*)&p_hi[px * 68 + cl0] = ph;
      *(s16x4*)&p_lo[px * 68 + cl0] = pl;
    }
    __syncthreads();
#pragma unroll
    for (int s = 0; s < 2; ++s) {
      int k0 = 32 * s + quad * 8;
      s16x8 bh = ld8(&p_hi[(16 * wv + l15) * 68 + k0]);
      s16x8 bl = ld8(&p_lo[(16 * wv + l15) * 68 + k0]);
      const short* whb = wo_hi + c * 64 + k0;
      const short* wlb = wo_lo + c * 64 + k0;
#pragma unroll
      for (int mt = 0; mt < 7; ++mt) {
        size_t ro = (size_t)(16 * mt + l15) * 2304;
        s16x8 ah = *(const s16x8*)(whb + ro);
        s16x8 al = *(const s16x8*)(wlb + ro);
        acc[mt] = __builtin_amdgcn_mfma_f32_16x16x32_bf16(ah, bh, acc[mt], 0, 0, 0);
        acc[mt] = __builtin_amdgcn_mfma_f32_16x16x32_bf16(ah, bl, acc[mt], 0, 0, 0);
        acc[mt] = __builtin_amdgcn_mfma_f32_16x16x32_bf16(al, bh, acc[mt], 0, 0, 0);
      }
    }
    __syncthreads();
  }

  int nb = 16 * wv + l15;
#pragma unroll
  for (int mt = 0; mt < 7; ++mt) {
#pragma unroll
    for (int r = 0; r < 4; ++r) {
      int co = 16 * mt + quad * 4 + r;
      if (co < 108)
        off[(((size_t)b * 108 + co) * 64 + h) * 64 + nb] = acc[mt][r] + b_off[co];
    }
  }
}

// DCN: round-1 proven VALU version, verbatim.
__global__ __launch_bounds__(256) void k_dcn(
    const float* __restrict__ x, const float* __restrict__ off,
    const float* __restrict__ w_dcn_t, const float* __restrict__ b_dcn,
    float* __restrict__ dcn) {
  __shared__ int4 s_idx[576];
  __shared__ float4 s_wgt[576];
  __shared__ float s_smp[72 * 64];

  int bi = blockIdx.x;  // B*G*H = 2048
  int h = bi & 63;
  int g = (bi >> 6) & 3;
  int b = bi >> 8;
  int tid = threadIdx.x;

  const float* offb = off + (size_t)b * 108 * 4096;
  for (int it = tid; it < 576; it += 256) {
    int kk = it >> 6;
    int w = it & 63;
    int sp = h * 64 + w;
    float oy = offb[((g * 9 + kk) * 2 + 0) * 4096 + sp];
    float ox = offb[((g * 9 + kk) * 2 + 1) * 4096 + sp];
    float mz = offb[(72 + g * 9 + kk) * 4096 + sp];
    float m = 1.f / (1.f + __expf(-mz));
    float py = (float)h + (float)(kk / 3 - 1) + oy;
    float pxf = (float)w + (float)(kk % 3 - 1) + ox;
    float y0 = floorf(py), x0 = floorf(pxf);
    float wy1 = py - y0, wy0 = 1.f - wy1;
    float wx1 = pxf - x0, wx0 = 1.f - wx1;
    int y0i = (int)y0, x0i = (int)x0;
    int y1i = y0i + 1, x1i = x0i + 1;
    bool vy0 = (y0i >= 0) & (y0i < 64), vy1 = (y1i >= 0) & (y1i < 64);
    bool vx0 = (x0i >= 0) & (x0i < 64), vx1 = (x1i >= 0) & (x1i < 64);
    int cy0 = min(max(y0i, 0), 63), cy1 = min(max(y1i, 0), 63);
    int cx0 = min(max(x0i, 0), 63), cx1 = min(max(x1i, 0), 63);
    s_idx[it] = make_int4(cy0 * 64 + cx0, cy0 * 64 + cx1,
                          cy1 * 64 + cx0, cy1 * 64 + cx1);
    s_wgt[it] = make_float4((vy0 && vx0) ? wy0 * wx0 * m : 0.f,
                            (vy0 && vx1) ? wy0 * wx1 * m : 0.f,
                            (vy1 && vx0) ? wy1 * wx0 * m : 0.f,
                            (vy1 && vx1) ? wy1 * wx1 * m : 0.f);
  }
  __syncthreads();

  int px = tid & 63, iq = tid >> 6;  // gather mapping
  int co = tid & 63, q = tid >> 6;   // matmul mapping
  float acc[16];
#pragma unroll
  for (int i = 0; i < 16; ++i) acc[i] = 0.f;

  for (int ch = 0; ch < 8; ++ch) {
    const float* xb = x + ((size_t)(b * 256 + g * 64 + ch * 8)) * 4096;
#pragma unroll 3
    for (int j = 0; j < 18; ++j) {
      int ckk_l = iq + 4 * j;  // 0..71
      int cl = ckk_l / 9, kk = ckk_l % 9;
      int it = kk * 64 + px;
      int4 id = s_idx[it];
      float4 wt = s_wgt[it];
      const float* xp = xb + cl * 4096;
      float v = wt.x * xp[id.x] + wt.y * xp[id.y] + wt.z * xp[id.z] +
                wt.w * xp[id.w];
      s_smp[ckk_l * 64 + px] = v;
    }
    __syncthreads();
    const float* wt = w_dcn_t + (g * 576 + ch * 72) * 64;
    for (int k = 0; k < 72; ++k) {
      float wv = wt[k * 64 + co];
      const float4* sp = (const float4*)&s_smp[k * 64 + q * 16];
#pragma unroll
      for (int i = 0; i < 4; ++i) {
        float4 sv = sp[i];
        acc[4 * i + 0] += wv * sv.x;
        acc[4 * i + 1] += wv * sv.y;
        acc[4 * i + 2] += wv * sv.z;
        acc[4 * i + 3] += wv * sv.w;
      }
    }
    __syncthreads();
  }
  float bias = b_dcn[g * 64 + co];
  float* o = dcn + (((size_t)(b * 256 + g * 64 + co)) * 64 + h) * 64 + q * 16;
#pragma unroll
  for (int i = 0; i < 16; ++i) o[i] = acc[i] + bias;
}

// LayerNorm over C + sigmoid + gate (round-1 verbatim).
__global__ __launch_bounds__(256) void k_ln(
    const float* __restrict__ dcn, const float* __restrict__ x,
    const float* __restrict__ gamma, const float* __restrict__ beta,
    float* __restrict__ out) {
  int p = blockIdx.x * 256 + threadIdx.x;  // 32768 pixels
  int b = p >> 12, hw = p & 4095;
  const float* ob = dcn + (size_t)b * 256 * 4096 + hw;
  const float* xb = x + (size_t)b * 256 * 4096 + hw;
  float* yb = out + (size_t)b * 256 * 4096 + hw;
  float s = 0.f, s2 = 0.f;
  for (int c = 0; c < 256; ++c) {
    float v = ob[c * 4096];
    s += v;
    s2 += v * v;
  }
  float mu = s * (1.f / 256.f);
  float var = s2 * (1.f / 256.f) - mu * mu;
  float rs = rsqrtf(var + 1e-5f);
  for (int c = 0; c < 256; ++c) {
    float v = ob[c * 4096];
    float nrm = (v - mu) * rs * gamma[c] + beta[c];
    float attn = 1.f / (1.f + __expf(-nrm));
    yb[c * 4096] = xb[c * 4096] * attn;
  }
}

extern "C" void kernel_launch(void* const* d_in, const int* in_sizes, int n_in,
                              void* d_out, int out_size, void* d_ws,
                              size_t ws_size, hipStream_t stream) {
  const float* x = (const float*)d_in[0];
  const float* w_off = (const float*)d_in[1];
  const float* b_off = (const float*)d_in[2];
  const float* w_dcn = (const float*)d_in[3];
  const float* b_dcn = (const float*)d_in[4];
  const float* gamma = (const float*)d_in[5];
  const float* beta = (const float*)d_in[6];
  float* out = (float*)d_out;
  char* wsb = (char*)d_ws;

  float* offb = (float*)wsb;
  float* dcnb = (float*)(wsb + 14155776);
  short* wo_hi = (short*)(wsb + 14155776);  // aliases dcnb (consumed first)
  short* wo_lo = (short*)(wsb + 14671872);
  float* w_dcn_t = (float*)(wsb + 47710208);

  k_prep<<<1584, 256, 0, stream>>>(w_off, w_dcn, wo_hi, wo_lo, w_dcn_t);
  k_offconv<<<512, 256, 0, stream>>>(x, wo_hi, wo_lo, b_off, offb);
  k_dcn<<<2048, 256, 0, stream>>>(x, offb, w_dcn_t, b_dcn, dcnb);
  k_ln<<<128, 256, 0, stream>>>(dcnb, x, gamma, beta, out);
}

// Round 5
// 685.260 us; speedup vs baseline: 1.3647x; 1.2680x over previous
//
#include <hip/hip_runtime.h>
#include <math.h>

// B=8, C=256, H=W=64, G=4, K=3, KK=9, Cg=64
// k_offconv: proven MFMA bf16-split (round-3/4 verbatim).
// k_dcn: MFMA bf16-split, inner loop transcribed 1:1 from the PROVEN offconv
//        structure (B-frag per-wave fixed, A-tiles iterated, offconv C-write).
// ws layout (bytes):
//   offb  fp32 [8][108][64][64]  @ 0          (14,155,776)
//   dcnb  fp32 [8][256][64][64]  @ 14,155,776 (33,554,432)
//     wo_hi short [112][2304]    @ 14,155,776 (516,096)  alias dcnb start;
//     wo_lo short [112][2304]    @ 14,671,872 (516,096)  consumed before dcnb written
//   wd_hi short [4][64][576]     @ 47,710,208 (294,912)  k = tap*64 + cl
//   wd_lo short [4][64][576]     @ 48,005,120 (294,912)
// total 48,300,032 B

typedef __attribute__((ext_vector_type(4))) short s16x4;
typedef __attribute__((ext_vector_type(8))) short s16x8;
typedef __attribute__((ext_vector_type(4))) float f32x4;

union S8 { s16x8 v; s16x4 h[2]; };

__device__ __forceinline__ s16x8 ld8(const short* p) {
  S8 r;
  r.h[0] = *(const s16x4*)p;
  r.h[1] = *(const s16x4*)(p + 4);
  return r.v;
}

__device__ __forceinline__ unsigned short bfr(float v) {  // RNE to bf16
  unsigned u = __float_as_uint(v);
  u = (u + 0x7FFFu + ((u >> 16) & 1u)) >> 16;
  return (unsigned short)u;
}
__device__ __forceinline__ float bff(unsigned short s) {
  return __uint_as_float(((unsigned)s) << 16);
}
__device__ __forceinline__ void split(float v, short& hi, short& lo) {
  unsigned short h = bfr(v);
  hi = (short)h;
  lo = (short)bfr(v - bff(h));  // exact residual in fp32
}

__global__ __launch_bounds__(256) void k_prep(
    const float* __restrict__ w_off, const float* __restrict__ w_dcn,
    short* __restrict__ wo_hi, short* __restrict__ wo_lo,
    short* __restrict__ wd_hi, short* __restrict__ wd_lo) {
  int i = blockIdx.x * 256 + threadIdx.x;
  const int n1 = 112 * 2304;
  if (i < n1) {
    int co = i / 2304, k = i % 2304;
    int tap = k >> 8, ch = k & 255;  // k = tap*256 + ch
    float v = (co < 108) ? w_off[(co * 256 + ch) * 9 + tap] : 0.f;
    short h, l;
    split(v, h, l);
    wo_hi[i] = h;
    wo_lo[i] = l;
  } else {
    int j = i - n1;  // exactly 147456 remaining threads
    int g = j / 36864, r = j % 36864;
    int co = r / 576, k = r % 576;
    int kk = k >> 6, cl = k & 63;  // k = tap*64 + cl
    float v = w_dcn[((g * 64 + co) * 64 + cl) * 9 + kk];
    short h, l;
    split(v, h, l);
    wd_hi[j] = h;
    wd_lo[j] = l;
  }
}

// Offset conv as bf16-split MFMA GEMM (round-3/4 verbatim — PROVEN).
__global__ __launch_bounds__(256) void k_offconv(
    const float* __restrict__ x, const short* __restrict__ wo_hi,
    const short* __restrict__ wo_lo, const float* __restrict__ b_off,
    float* __restrict__ off) {
  __shared__ short p_hi[64 * 68];
  __shared__ short p_lo[64 * 68];
  int b = blockIdx.x >> 6, h = blockIdx.x & 63;
  int tid = threadIdx.x;
  int px = tid & 63, iq = tid >> 6;
  int lane = tid & 63, wv = tid >> 6;
  int quad = lane >> 4, l15 = lane & 15;

  f32x4 zero4 = {0.f, 0.f, 0.f, 0.f};
  f32x4 acc[7];
#pragma unroll
  for (int i = 0; i < 7; ++i) acc[i] = zero4;

  const float* xb = x + (size_t)b * 256 * 4096;

  for (int c = 0; c < 36; ++c) {
    int tap = c >> 2, ch0 = (c & 3) << 6;
    int ky = tap / 3, kx = tap % 3;
    int hh = h - 1 + ky;
    int col = px - 1 + kx;
    bool vok = ((unsigned)hh < 64u) & ((unsigned)col < 64u);
    const float* xrow = xb + (size_t)ch0 * 4096 + hh * 64 + col;
#pragma unroll
    for (int j = 0; j < 4; ++j) {
      int cl0 = 4 * iq + 16 * j;
      s16x4 ph, pl;
#pragma unroll
      for (int m = 0; m < 4; ++m) {
        float v = vok ? xrow[(size_t)(cl0 + m) * 4096] : 0.f;
        short hv, lv;
        split(v, hv, lv);
        ph[m] = hv;
        pl[m] = lv;
      }
      *(s16x4*)&p_hi[px * 68 + cl0] = ph;
      *(s16x4*)&p_lo[px * 68 + cl0] = pl;
    }
    __syncthreads();
#pragma unroll
    for (int s = 0; s < 2; ++s) {
      int k0 = 32 * s + quad * 8;
      s16x8 bh = ld8(&p_hi[(16 * wv + l15) * 68 + k0]);
      s16x8 bl = ld8(&p_lo[(16 * wv + l15) * 68 + k0]);
      const short* whb = wo_hi + c * 64 + k0;
      const short* wlb = wo_lo + c * 64 + k0;
#pragma unroll
      for (int mt = 0; mt < 7; ++mt) {
        size_t ro = (size_t)(16 * mt + l15) * 2304;
        s16x8 ah = *(const s16x8*)(whb + ro);
        s16x8 al = *(const s16x8*)(wlb + ro);
        acc[mt] = __builtin_amdgcn_mfma_f32_16x16x32_bf16(ah, bh, acc[mt], 0, 0, 0);
        acc[mt] = __builtin_amdgcn_mfma_f32_16x16x32_bf16(ah, bl, acc[mt], 0, 0, 0);
        acc[mt] = __builtin_amdgcn_mfma_f32_16x16x32_bf16(al, bh, acc[mt], 0, 0, 0);
      }
    }
    __syncthreads();
  }

  int nb = 16 * wv + l15;
#pragma unroll
  for (int mt = 0; mt < 7; ++mt) {
#pragma unroll
    for (int r = 0; r < 4; ++r) {
      int co = 16 * mt + quad * 4 + r;
      if (co < 108)
        off[(((size_t)b * 108 + co) * 64 + h) * 64 + nb] = acc[mt][r] + b_off[co];
    }
  }
}

// DCN as bf16-split MFMA GEMM, offconv-structured.
// Block=(b,g,h): out[64co][64px] = W[64][576] x S[576][64]. 9 K-chunks (tap).
// Per-wave fixed B-frag (pixel tile 16*wv), A-tiles mt=0..3 iterated.
__global__ __launch_bounds__(256) void k_dcn(
    const float* __restrict__ x, const float* __restrict__ off,
    const short* __restrict__ wd_hi, const short* __restrict__ wd_lo,
    const float* __restrict__ b_dcn, float* __restrict__ dcn) {
  __shared__ int4 s_idx[576];
  __shared__ float4 s_wgt[576];
  __shared__ short p_hi[64 * 68];
  __shared__ short p_lo[64 * 68];

  int bi = blockIdx.x;  // B*G*H = 2048
  int h = bi & 63, g = (bi >> 6) & 3, b = bi >> 8;
  int tid = threadIdx.x;
  int px = tid & 63, iq = tid >> 6;
  int lane = tid & 63, wv = tid >> 6;
  int quad = lane >> 4, l15 = lane & 15;

  // phase 1: sampling params (item = kk*64 + w) — round-1/4 proven verbatim
  const float* offb = off + (size_t)b * 108 * 4096;
  for (int it = tid; it < 576; it += 256) {
    int kk = it >> 6;
    int w = it & 63;
    int sp = h * 64 + w;
    float oy = offb[((g * 9 + kk) * 2 + 0) * 4096 + sp];
    float ox = offb[((g * 9 + kk) * 2 + 1) * 4096 + sp];
    float mz = offb[(72 + g * 9 + kk) * 4096 + sp];
    float m = 1.f / (1.f + __expf(-mz));
    float py = (float)h + (float)(kk / 3 - 1) + oy;
    float pxf = (float)w + (float)(kk % 3 - 1) + ox;
    float y0 = floorf(py), x0 = floorf(pxf);
    float wy1 = py - y0, wy0 = 1.f - wy1;
    float wx1 = pxf - x0, wx0 = 1.f - wx1;
    int y0i = (int)y0, x0i = (int)x0;
    int y1i = y0i + 1, x1i = x0i + 1;
    bool vy0 = (y0i >= 0) & (y0i < 64), vy1 = (y1i >= 0) & (y1i < 64);
    bool vx0 = (x0i >= 0) & (x0i < 64), vx1 = (x1i >= 0) & (x1i < 64);
    int cy0 = min(max(y0i, 0), 63), cy1 = min(max(y1i, 0), 63);
    int cx0 = min(max(x0i, 0), 63), cx1 = min(max(x1i, 0), 63);
    s_idx[it] = make_int4(cy0 * 64 + cx0, cy0 * 64 + cx1,
                          cy1 * 64 + cx0, cy1 * 64 + cx1);
    s_wgt[it] = make_float4((vy0 && vx0) ? wy0 * wx0 * m : 0.f,
                            (vy0 && vx1) ? wy0 * wx1 * m : 0.f,
                            (vy1 && vx0) ? wy1 * wx0 * m : 0.f,
                            (vy1 && vx1) ? wy1 * wx1 * m : 0.f);
  }
  __syncthreads();

  f32x4 zero4 = {0.f, 0.f, 0.f, 0.f};
  f32x4 acc[4];
#pragma unroll
  for (int i = 0; i < 4; ++i) acc[i] = zero4;

  const float* xg = x + ((size_t)b * 256 + g * 64) * 4096;

  for (int c = 0; c < 9; ++c) {
    int4 id = s_idx[c * 64 + px];
    float4 wt = s_wgt[c * 64 + px];
#pragma unroll
    for (int j = 0; j < 4; ++j) {
      int cl0 = 4 * iq + 16 * j;
      s16x4 ph, pl;
#pragma unroll
      for (int m = 0; m < 4; ++m) {
        const float* xp = xg + (size_t)(cl0 + m) * 4096;
        float v = wt.x * xp[id.x] + wt.y * xp[id.y] + wt.z * xp[id.z] +
                  wt.w * xp[id.w];
        short hv, lv;
        split(v, hv, lv);
        ph[m] = hv;
        pl[m] = lv;
      }
      *(s16x4*)&p_hi[px * 68 + cl0] = ph;
      *(s16x4*)&p_lo[px * 68 + cl0] = pl;
    }
    __syncthreads();
#pragma unroll
    for (int s = 0; s < 2; ++s) {
      int k0 = 32 * s + quad * 8;
      s16x8 bh = ld8(&p_hi[(16 * wv + l15) * 68 + k0]);
      s16x8 bl = ld8(&p_lo[(16 * wv + l15) * 68 + k0]);
      const short* whb = wd_hi + (size_t)g * 36864 + c * 64 + k0;
      const short* wlb = wd_lo + (size_t)g * 36864 + c * 64 + k0;
#pragma unroll
      for (int mt = 0; mt < 4; ++mt) {
        size_t ro = (size_t)(16 * mt + l15) * 576;
        s16x8 ah = *(const s16x8*)(whb + ro);
        s16x8 al = *(const s16x8*)(wlb + ro);
        acc[mt] = __builtin_amdgcn_mfma_f32_16x16x32_bf16(ah, bh, acc[mt], 0, 0, 0);
        acc[mt] = __builtin_amdgcn_mfma_f32_16x16x32_bf16(ah, bl, acc[mt], 0, 0, 0);
        acc[mt] = __builtin_amdgcn_mfma_f32_16x16x32_bf16(al, bh, acc[mt], 0, 0, 0);
      }
    }
    __syncthreads();
  }

  int nb = 16 * wv + l15;
#pragma unroll
  for (int mt = 0; mt < 4; ++mt) {
#pragma unroll
    for (int r = 0; r < 4; ++r) {
      int co = 16 * mt + quad * 4 + r;
      dcn[(((size_t)b * 256 + g * 64 + co) * 64 + h) * 64 + nb] =
          acc[mt][r] + b_dcn[g * 64 + co];
    }
  }
}

// LayerNorm over C + sigmoid + gate (round-1/4 verbatim).
__global__ __launch_bounds__(256) void k_ln(
    const float* __restrict__ dcn, const float* __restrict__ x,
    const float* __restrict__ gamma, const float* __restrict__ beta,
    float* __restrict__ out) {
  int p = blockIdx.x * 256 + threadIdx.x;  // 32768 pixels
  int b = p >> 12, hw = p & 4095;
  const float* ob = dcn + (size_t)b * 256 * 4096 + hw;
  const float* xb = x + (size_t)b * 256 * 4096 + hw;
  float* yb = out + (size_t)b * 256 * 4096 + hw;
  float s = 0.f, s2 = 0.f;
  for (int c = 0; c < 256; ++c) {
    float v = ob[c * 4096];
    s += v;
    s2 += v * v;
  }
  float mu = s * (1.f / 256.f);
  float var = s2 * (1.f / 256.f) - mu * mu;
  float rs = rsqrtf(var + 1e-5f);
  for (int c = 0; c < 256; ++c) {
    float v = ob[c * 4096];
    float nrm = (v - mu) * rs * gamma[c] + beta[c];
    float attn = 1.f / (1.f + __expf(-nrm));
    yb[c * 4096] = xb[c * 4096] * attn;
  }
}

extern "C" void kernel_launch(void* const* d_in, const int* in_sizes, int n_in,
                              void* d_out, int out_size, void* d_ws,
                              size_t ws_size, hipStream_t stream) {
  const float* x = (const float*)d_in[0];
  const float* w_off = (const float*)d_in[1];
  const float* b_off = (const float*)d_in[2];
  const float* w_dcn = (const float*)d_in[3];
  const float* b_dcn = (const float*)d_in[4];
  const float* gamma = (const float*)d_in[5];
  const float* beta = (const float*)d_in[6];
  float* out = (float*)d_out;
  char* wsb = (char*)d_ws;

  float* offb = (float*)wsb;
  float* dcnb = (float*)(wsb + 14155776);
  short* wo_hi = (short*)(wsb + 14155776);  // aliases dcnb (consumed first)
  short* wo_lo = (short*)(wsb + 14671872);
  short* wd_hi = (short*)(wsb + 47710208);
  short* wd_lo = (short*)(wsb + 48005120);

  k_prep<<<1584, 256, 0, stream>>>(w_off, w_dcn, wo_hi, wo_lo, wd_hi, wd_lo);
  k_offconv<<<512, 256, 0, stream>>>(x, wo_hi, wo_lo, b_off, offb);
  k_dcn<<<2048, 256, 0, stream>>>(x, offb, wd_hi, wd_lo, b_dcn, dcnb);
  k_ln<<<128, 256, 0, stream>>>(dcnb, x, gamma, beta, out);
}

// Round 6
// 682.973 us; speedup vs baseline: 1.3693x; 1.0033x over previous
//
#include <hip/hip_runtime.h>
#include <math.h>

// B=8, C=256, H=W=64, G=4, K=3, KK=9, Cg=64
// Round 6: occupancy round.
//  - k_offconv: 4-way M-split (grid 2048, 8 blocks/CU, 100% occ)
//  - k_dcn: sampling params computed per-chunk in registers (no s_idx/s_wgt
//    LDS, no phase-1) -> LDS 17.4 KB, 8 blocks/CU
//  - k_ln: 4-way channel split per pixel, grid 512
// ws layout (bytes):
//   offb  fp32 [8][108][64][64]  @ 0          (14,155,776)
//   dcnb  fp32 [8][256][64][64]  @ 14,155,776 (33,554,432)
//     wo_hi short [112][2304]    @ 14,155,776 (516,096)  alias dcnb start;
//     wo_lo short [112][2304]    @ 14,671,872 (516,096)  consumed before dcnb written
//   wd_hi short [4][64][576]     @ 47,710,208 (294,912)  k = tap*64 + cl
//   wd_lo short [4][64][576]     @ 48,005,120 (294,912)
// total 48,300,032 B

typedef __attribute__((ext_vector_type(4))) short s16x4;
typedef __attribute__((ext_vector_type(8))) short s16x8;
typedef __attribute__((ext_vector_type(4))) float f32x4;

union S8 { s16x8 v; s16x4 h[2]; };

__device__ __forceinline__ s16x8 ld8(const short* p) {
  S8 r;
  r.h[0] = *(const s16x4*)p;
  r.h[1] = *(const s16x4*)(p + 4);
  return r.v;
}

__device__ __forceinline__ unsigned short bfr(float v) {  // RNE to bf16
  unsigned u = __float_as_uint(v);
  u = (u + 0x7FFFu + ((u >> 16) & 1u)) >> 16;
  return (unsigned short)u;
}
__device__ __forceinline__ float bff(unsigned short s) {
  return __uint_as_float(((unsigned)s) << 16);
}
__device__ __forceinline__ void split(float v, short& hi, short& lo) {
  unsigned short h = bfr(v);
  hi = (short)h;
  lo = (short)bfr(v - bff(h));  // exact residual in fp32
}

__global__ __launch_bounds__(256) void k_prep(
    const float* __restrict__ w_off, const float* __restrict__ w_dcn,
    short* __restrict__ wo_hi, short* __restrict__ wo_lo,
    short* __restrict__ wd_hi, short* __restrict__ wd_lo) {
  int i = blockIdx.x * 256 + threadIdx.x;
  const int n1 = 112 * 2304;
  if (i < n1) {
    int co = i / 2304, k = i % 2304;
    int tap = k >> 8, ch = k & 255;  // k = tap*256 + ch
    float v = (co < 108) ? w_off[(co * 256 + ch) * 9 + tap] : 0.f;
    short h, l;
    split(v, h, l);
    wo_hi[i] = h;
    wo_lo[i] = l;
  } else {
    int j = i - n1;  // exactly 147456 remaining threads
    int g = j / 36864, r = j % 36864;
    int co = r / 576, k = r % 576;
    int kk = k >> 6, cl = k & 63;  // k = tap*64 + cl
    float v = w_dcn[((g * 64 + co) * 64 + cl) * 9 + kk];
    short h, l;
    split(v, h, l);
    wd_hi[j] = h;
    wd_lo[j] = l;
  }
}

// Offset conv, bf16-split MFMA. Block=(b,h,part): part handles M-tiles
// {2*part, 2*part+1} (mt<7). Grid = 2048 -> 8 blocks/CU.
__global__ __launch_bounds__(256) void k_offconv(
    const float* __restrict__ x, const short* __restrict__ wo_hi,
    const short* __restrict__ wo_lo, const float* __restrict__ b_off,
    float* __restrict__ off) {
  __shared__ short p_hi[64 * 68];
  __shared__ short p_lo[64 * 68];
  int part = blockIdx.x & 3;
  int bh = blockIdx.x >> 2;
  int b = bh >> 6, h = bh & 63;
  int mt0 = part * 2;
  int tid = threadIdx.x;
  int px = tid & 63, iq = tid >> 6;
  int lane = tid & 63, wv = tid >> 6;
  int quad = lane >> 4, l15 = lane & 15;

  f32x4 zero4 = {0.f, 0.f, 0.f, 0.f};
  f32x4 acc[2];
  acc[0] = zero4;
  acc[1] = zero4;

  const float* xb = x + (size_t)b * 256 * 4096;

  for (int c = 0; c < 36; ++c) {
    int tap = c >> 2, ch0 = (c & 3) << 6;
    int ky = tap / 3, kx = tap % 3;
    int hh = h - 1 + ky;
    int col = px - 1 + kx;
    bool vok = ((unsigned)hh < 64u) & ((unsigned)col < 64u);
    const float* xrow = xb + (size_t)ch0 * 4096 + hh * 64 + col;
#pragma unroll
    for (int j = 0; j < 4; ++j) {
      int cl0 = 4 * iq + 16 * j;
      s16x4 ph, pl;
#pragma unroll
      for (int m = 0; m < 4; ++m) {
        float v = vok ? xrow[(size_t)(cl0 + m) * 4096] : 0.f;
        short hv, lv;
        split(v, hv, lv);
        ph[m] = hv;
        pl[m] = lv;
      }
      *(s16x4*)&p_hi[px * 68 + cl0] = ph;
      *(s16x4*)&p_lo[px * 68 + cl0] = pl;
    }
    __syncthreads();
#pragma unroll
    for (int s = 0; s < 2; ++s) {
      int k0 = 32 * s + quad * 8;
      s16x8 bh_f = ld8(&p_hi[(16 * wv + l15) * 68 + k0]);
      s16x8 bl_f = ld8(&p_lo[(16 * wv + l15) * 68 + k0]);
      const short* whb = wo_hi + c * 64 + k0;
      const short* wlb = wo_lo + c * 64 + k0;
#pragma unroll
      for (int mi = 0; mi < 2; ++mi) {
        int mt = mt0 + mi;
        if (mt < 7) {
          size_t ro = (size_t)(16 * mt + l15) * 2304;
          s16x8 ah = *(const s16x8*)(whb + ro);
          s16x8 al = *(const s16x8*)(wlb + ro);
          acc[mi] = __builtin_amdgcn_mfma_f32_16x16x32_bf16(ah, bh_f, acc[mi], 0, 0, 0);
          acc[mi] = __builtin_amdgcn_mfma_f32_16x16x32_bf16(ah, bl_f, acc[mi], 0, 0, 0);
          acc[mi] = __builtin_amdgcn_mfma_f32_16x16x32_bf16(al, bh_f, acc[mi], 0, 0, 0);
        }
      }
    }
    __syncthreads();
  }

  int nb = 16 * wv + l15;
#pragma unroll
  for (int mi = 0; mi < 2; ++mi) {
    int mt = mt0 + mi;
    if (mt < 7) {
#pragma unroll
      for (int r = 0; r < 4; ++r) {
        int co = 16 * mt + quad * 4 + r;
        if (co < 108)
          off[(((size_t)b * 108 + co) * 64 + h) * 64 + nb] = acc[mi][r] + b_off[co];
      }
    }
  }
}

// DCN, bf16-split MFMA, offconv-structured (proven round-5 inner loop).
// Sampling params now computed per-chunk in registers (column px per thread).
__global__ __launch_bounds__(256) void k_dcn(
    const float* __restrict__ x, const float* __restrict__ off,
    const short* __restrict__ wd_hi, const short* __restrict__ wd_lo,
    const float* __restrict__ b_dcn, float* __restrict__ dcn) {
  __shared__ short p_hi[64 * 68];
  __shared__ short p_lo[64 * 68];

  int bi = blockIdx.x;  // B*G*H = 2048
  int h = bi & 63, g = (bi >> 6) & 3, b = bi >> 8;
  int tid = threadIdx.x;
  int px = tid & 63, iq = tid >> 6;
  int lane = tid & 63, wv = tid >> 6;
  int quad = lane >> 4, l15 = lane & 15;

  f32x4 zero4 = {0.f, 0.f, 0.f, 0.f};
  f32x4 acc[4];
#pragma unroll
  for (int i = 0; i < 4; ++i) acc[i] = zero4;

  const float* xg = x + ((size_t)b * 256 + g * 64) * 4096;
  const float* offb = off + (size_t)b * 108 * 4096;
  int sp = h * 64 + px;

  for (int c = 0; c < 9; ++c) {
    // sampling params for (tap c, column px) — round-5 phase-1 math verbatim
    float oy = offb[((g * 9 + c) * 2 + 0) * 4096 + sp];
    float ox = offb[((g * 9 + c) * 2 + 1) * 4096 + sp];
    float mz = offb[(72 + g * 9 + c) * 4096 + sp];
    float m = 1.f / (1.f + __expf(-mz));
    float py = (float)h + (float)(c / 3 - 1) + oy;
    float pxf = (float)px + (float)(c % 3 - 1) + ox;
    float y0 = floorf(py), x0 = floorf(pxf);
    float wy1 = py - y0, wy0 = 1.f - wy1;
    float wx1 = pxf - x0, wx0 = 1.f - wx1;
    int y0i = (int)y0, x0i = (int)x0;
    int y1i = y0i + 1, x1i = x0i + 1;
    bool vy0 = (y0i >= 0) & (y0i < 64), vy1 = (y1i >= 0) & (y1i < 64);
    bool vx0 = (x0i >= 0) & (x0i < 64), vx1 = (x1i >= 0) & (x1i < 64);
    int cy0 = min(max(y0i, 0), 63), cy1 = min(max(y1i, 0), 63);
    int cx0 = min(max(x0i, 0), 63), cx1 = min(max(x1i, 0), 63);
    int4 id = make_int4(cy0 * 64 + cx0, cy0 * 64 + cx1,
                        cy1 * 64 + cx0, cy1 * 64 + cx1);
    float4 wt = make_float4((vy0 && vx0) ? wy0 * wx0 * m : 0.f,
                            (vy0 && vx1) ? wy0 * wx1 * m : 0.f,
                            (vy1 && vx0) ? wy1 * wx0 * m : 0.f,
                            (vy1 && vx1) ? wy1 * wx1 * m : 0.f);
#pragma unroll
    for (int j = 0; j < 4; ++j) {
      int cl0 = 4 * iq + 16 * j;
      s16x4 ph, pl;
#pragma unroll
      for (int mm = 0; mm < 4; ++mm) {
        const float* xp = xg + (size_t)(cl0 + mm) * 4096;
        float v = wt.x * xp[id.x] + wt.y * xp[id.y] + wt.z * xp[id.z] +
                  wt.w * xp[id.w];
        short hv, lv;
        split(v, hv, lv);
        ph[mm] = hv;
        pl[mm] = lv;
      }
      *(s16x4*)&p_hi[px * 68 + cl0] = ph;
      *(s16x4*)&p_lo[px * 68 + cl0] = pl;
    }
    __syncthreads();
#pragma unroll
    for (int s = 0; s < 2; ++s) {
      int k0 = 32 * s + quad * 8;
      s16x8 bh_f = ld8(&p_hi[(16 * wv + l15) * 68 + k0]);
      s16x8 bl_f = ld8(&p_lo[(16 * wv + l15) * 68 + k0]);
      const short* whb = wd_hi + (size_t)g * 36864 + c * 64 + k0;
      const short* wlb = wd_lo + (size_t)g * 36864 + c * 64 + k0;
#pragma unroll
      for (int mt = 0; mt < 4; ++mt) {
        size_t ro = (size_t)(16 * mt + l15) * 576;
        s16x8 ah = *(const s16x8*)(whb + ro);
        s16x8 al = *(const s16x8*)(wlb + ro);
        acc[mt] = __builtin_amdgcn_mfma_f32_16x16x32_bf16(ah, bh_f, acc[mt], 0, 0, 0);
        acc[mt] = __builtin_amdgcn_mfma_f32_16x16x32_bf16(ah, bl_f, acc[mt], 0, 0, 0);
        acc[mt] = __builtin_amdgcn_mfma_f32_16x16x32_bf16(al, bh_f, acc[mt], 0, 0, 0);
      }
    }
    __syncthreads();
  }

  int nb = 16 * wv + l15;
#pragma unroll
  for (int mt = 0; mt < 4; ++mt) {
#pragma unroll
    for (int r = 0; r < 4; ++r) {
      int co = 16 * mt + quad * 4 + r;
      dcn[(((size_t)b * 256 + g * 64 + co) * 64 + h) * 64 + nb] =
          acc[mt][r] + b_dcn[g * 64 + co];
    }
  }
}

// LayerNorm over C + sigmoid + gate. Block = 64 pixels x 4 channel-parts.
// Grid 512. Each thread sums 64 channels; LDS reduce across parts.
__global__ __launch_bounds__(256) void k_ln(
    const float* __restrict__ dcn, const float* __restrict__ x,
    const float* __restrict__ gamma, const float* __restrict__ beta,
    float* __restrict__ out) {
  __shared__ float red_s[4][64];
  __shared__ float red_q[4][64];
  int px = threadIdx.x & 63;
  int part = threadIdx.x >> 6;
  int p = blockIdx.x * 64 + px;  // 32768 pixels
  int b = p >> 12, hw = p & 4095;
  const float* ob = dcn + (size_t)b * 256 * 4096 + hw;
  const float* xb = x + (size_t)b * 256 * 4096 + hw;
  float* yb = out + (size_t)b * 256 * 4096 + hw;
  int c0 = part * 64;
  float s = 0.f, s2 = 0.f;
  for (int c = c0; c < c0 + 64; ++c) {
    float v = ob[c * 4096];
    s += v;
    s2 += v * v;
  }
  red_s[part][px] = s;
  red_q[part][px] = s2;
  __syncthreads();
  s = red_s[0][px] + red_s[1][px] + red_s[2][px] + red_s[3][px];
  s2 = red_q[0][px] + red_q[1][px] + red_q[2][px] + red_q[3][px];
  float mu = s * (1.f / 256.f);
  float var = s2 * (1.f / 256.f) - mu * mu;
  float rs = rsqrtf(var + 1e-5f);
  for (int c = c0; c < c0 + 64; ++c) {
    float v = ob[c * 4096];
    float nrm = (v - mu) * rs * gamma[c] + beta[c];
    float attn = 1.f / (1.f + __expf(-nrm));
    yb[c * 4096] = xb[c * 4096] * attn;
  }
}

extern "C" void kernel_launch(void* const* d_in, const int* in_sizes, int n_in,
                              void* d_out, int out_size, void* d_ws,
                              size_t ws_size, hipStream_t stream) {
  const float* x = (const float*)d_in[0];
  const float* w_off = (const float*)d_in[1];
  const float* b_off = (const float*)d_in[2];
  const float* w_dcn = (const float*)d_in[3];
  const float* b_dcn = (const float*)d_in[4];
  const float* gamma = (const float*)d_in[5];
  const float* beta = (const float*)d_in[6];
  float* out = (float*)d_out;
  char* wsb = (char*)d_ws;

  float* offb = (float*)wsb;
  float* dcnb = (float*)(wsb + 14155776);
  short* wo_hi = (short*)(wsb + 14155776);  // aliases dcnb (consumed first)
  short* wo_lo = (short*)(wsb + 14671872);
  short* wd_hi = (short*)(wsb + 47710208);
  short* wd_lo = (short*)(wsb + 48005120);

  k_prep<<<1584, 256, 0, stream>>>(w_off, w_dcn, wo_hi, wo_lo, wd_hi, wd_lo);
  k_offconv<<<2048, 256, 0, stream>>>(x, wo_hi, wo_lo, b_off, offb);
  k_dcn<<<2048, 256, 0, stream>>>(x, offb, wd_hi, wd_lo, b_dcn, dcnb);
  k_ln<<<512, 256, 0, stream>>>(dcnb, x, gamma, beta, out);
}

// Round 7
// 524.838 us; speedup vs baseline: 1.7818x; 1.3013x over previous
//
#include <hip/hip_runtime.h>
#include <math.h>

// B=8, C=256, H=W=64, G=4, K=3, KK=9, Cg=64
// Round 7: redundancy-free round, single-bf16 (no hi/lo split).
//  - k_offconv: K-split by channel-quarter (part reads DISJOINT channels ->
//    no fetch duplication), writes bf16 partials; k_dcn folds the 4-way sum.
//  - k_dcn: round-6 proven structure, minus split, plus partial-sum off reads.
//  - dcn output lives in d_out (k_ln is in-place safe).
// ws layout (bytes):
//   wpart bf16 [4][8][108][4096] @ 0          (28,311,552)
//   wo_a  bf16 [112][2304]       @ 28,311,552 (516,096)   k = tap*256+ch
//   wd_a  bf16 [4][64][576]      @ 28,827,648 (294,912)   k = tap*64+cl
// total 29,122,560 B (< proven 48.3 MB)

typedef __attribute__((ext_vector_type(4))) short s16x4;
typedef __attribute__((ext_vector_type(8))) short s16x8;
typedef __attribute__((ext_vector_type(4))) float f32x4;

union S8 { s16x8 v; s16x4 h[2]; };

__device__ __forceinline__ s16x8 ld8(const short* p) {
  S8 r;
  r.h[0] = *(const s16x4*)p;
  r.h[1] = *(const s16x4*)(p + 4);
  return r.v;
}

__device__ __forceinline__ unsigned short bfr(float v) {  // RNE to bf16
  unsigned u = __float_as_uint(v);
  u = (u + 0x7FFFu + ((u >> 16) & 1u)) >> 16;
  return (unsigned short)u;
}
__device__ __forceinline__ float bff(unsigned short s) {
  return __uint_as_float(((unsigned)s) << 16);
}

__global__ __launch_bounds__(256) void k_prep(
    const float* __restrict__ w_off, const float* __restrict__ w_dcn,
    short* __restrict__ wo_a, short* __restrict__ wd_a) {
  int i = blockIdx.x * 256 + threadIdx.x;
  const int n1 = 112 * 2304;
  if (i < n1) {
    int co = i / 2304, k = i % 2304;
    int tap = k >> 8, ch = k & 255;  // k = tap*256 + ch
    float v = (co < 108) ? w_off[(co * 256 + ch) * 9 + tap] : 0.f;
    wo_a[i] = (short)bfr(v);
  } else {
    int j = i - n1;  // exactly 147456 remaining threads (grid 1584*256)
    int g = j / 36864, r = j % 36864;
    int co = r / 576, k = r % 576;
    int kk = k >> 6, cl = k & 63;  // k = tap*64 + cl
    wd_a[j] = (short)bfr(w_dcn[((g * 64 + co) * 64 + cl) * 9 + kk]);
  }
}

// Offset conv, bf16 MFMA, K-split by channel-quarter.
// blockIdx = part*512 + (b*64+h); part handles channels [64*part, 64*part+64)
// over all 9 taps (9 K-chunks of 64), producing a bf16 PARTIAL of out[108][64].
__global__ __launch_bounds__(256) void k_offconv(
    const float* __restrict__ x, const short* __restrict__ wo_a,
    const float* __restrict__ b_off, short* __restrict__ wpart) {
  __shared__ short p_s[64 * 68];
  int part = blockIdx.x >> 9;
  int bh = blockIdx.x & 511;
  int b = bh >> 6, h = bh & 63;
  int tid = threadIdx.x;
  int px = tid & 63, iq = tid >> 6;
  int lane = tid & 63, wv = tid >> 6;
  int quad = lane >> 4, l15 = lane & 15;

  f32x4 zero4 = {0.f, 0.f, 0.f, 0.f};
  f32x4 acc[7];
#pragma unroll
  for (int i = 0; i < 7; ++i) acc[i] = zero4;

  const float* xb = x + ((size_t)b * 256 + part * 64) * 4096;

  for (int tap = 0; tap < 9; ++tap) {
    int ky = tap / 3, kx = tap % 3;
    int hh = h - 1 + ky;
    int col = px - 1 + kx;
    bool vok = ((unsigned)hh < 64u) & ((unsigned)col < 64u);
    const float* xrow = xb + hh * 64 + col;
#pragma unroll
    for (int j = 0; j < 4; ++j) {
      int cl0 = 4 * iq + 16 * j;
      s16x4 ph;
#pragma unroll
      for (int m = 0; m < 4; ++m) {
        float v = vok ? xrow[(size_t)(cl0 + m) * 4096] : 0.f;
        ph[m] = (short)bfr(v);
      }
      *(s16x4*)&p_s[px * 68 + cl0] = ph;
    }
    __syncthreads();
#pragma unroll
    for (int s = 0; s < 2; ++s) {
      int k0 = 32 * s + quad * 8;
      s16x8 bf_f = ld8(&p_s[(16 * wv + l15) * 68 + k0]);
      const short* wb = wo_a + tap * 256 + part * 64 + k0;
#pragma unroll
      for (int mt = 0; mt < 7; ++mt) {
        s16x8 af = *(const s16x8*)(wb + (size_t)(16 * mt + l15) * 2304);
        acc[mt] = __builtin_amdgcn_mfma_f32_16x16x32_bf16(af, bf_f, acc[mt], 0, 0, 0);
      }
    }
    __syncthreads();
  }

  int nb = 16 * wv + l15;
  short* wp = wpart + ((size_t)part * 8 + b) * 108 * 4096;
#pragma unroll
  for (int mt = 0; mt < 7; ++mt) {
#pragma unroll
    for (int r = 0; r < 4; ++r) {
      int co = 16 * mt + quad * 4 + r;
      if (co < 108) {
        float v = acc[mt][r] + (part == 0 ? b_off[co] : 0.f);
        wp[(size_t)co * 4096 + h * 64 + nb] = (short)bfr(v);
      }
    }
  }
}

// DCN, bf16 MFMA, round-6 proven structure. Offsets/mask logits come as the
// sum of 4 bf16 partials from wpart.
__global__ __launch_bounds__(256) void k_dcn(
    const float* __restrict__ x, const short* __restrict__ wpart,
    const short* __restrict__ wd_a, const float* __restrict__ b_dcn,
    float* __restrict__ dcn) {
  __shared__ short p_s[64 * 68];

  int bi = blockIdx.x;  // B*G*H = 2048
  int h = bi & 63, g = (bi >> 6) & 3, b = bi >> 8;
  int tid = threadIdx.x;
  int px = tid & 63, iq = tid >> 6;
  int lane = tid & 63, wv = tid >> 6;
  int quad = lane >> 4, l15 = lane & 15;

  f32x4 zero4 = {0.f, 0.f, 0.f, 0.f};
  f32x4 acc[4];
#pragma unroll
  for (int i = 0; i < 4; ++i) acc[i] = zero4;

  const float* xg = x + ((size_t)b * 256 + g * 64) * 4096;
  int sp = h * 64 + px;

  for (int c = 0; c < 9; ++c) {
    // offset/mask params for (tap c, column px): fold 4 bf16 partials
    int co_y = (g * 9 + c) * 2;
    float oy = 0.f, ox = 0.f, mz = 0.f;
#pragma unroll
    for (int p4 = 0; p4 < 4; ++p4) {
      const short* wp = wpart + ((size_t)p4 * 8 + b) * 108 * 4096;
      oy += bff((unsigned short)wp[(size_t)co_y * 4096 + sp]);
      ox += bff((unsigned short)wp[(size_t)(co_y + 1) * 4096 + sp]);
      mz += bff((unsigned short)wp[(size_t)(72 + g * 9 + c) * 4096 + sp]);
    }
    float m = 1.f / (1.f + __expf(-mz));
    float py = (float)h + (float)(c / 3 - 1) + oy;
    float pxf = (float)px + (float)(c % 3 - 1) + ox;
    float y0 = floorf(py), x0 = floorf(pxf);
    float wy1 = py - y0, wy0 = 1.f - wy1;
    float wx1 = pxf - x0, wx0 = 1.f - wx1;
    int y0i = (int)y0, x0i = (int)x0;
    int y1i = y0i + 1, x1i = x0i + 1;
    bool vy0 = (y0i >= 0) & (y0i < 64), vy1 = (y1i >= 0) & (y1i < 64);
    bool vx0 = (x0i >= 0) & (x0i < 64), vx1 = (x1i >= 0) & (x1i < 64);
    int cy0 = min(max(y0i, 0), 63), cy1 = min(max(y1i, 0), 63);
    int cx0 = min(max(x0i, 0), 63), cx1 = min(max(x1i, 0), 63);
    int4 id = make_int4(cy0 * 64 + cx0, cy0 * 64 + cx1,
                        cy1 * 64 + cx0, cy1 * 64 + cx1);
    float4 wt = make_float4((vy0 && vx0) ? wy0 * wx0 * m : 0.f,
                            (vy0 && vx1) ? wy0 * wx1 * m : 0.f,
                            (vy1 && vx0) ? wy1 * wx0 * m : 0.f,
                            (vy1 && vx1) ? wy1 * wx1 * m : 0.f);
#pragma unroll
    for (int j = 0; j < 4; ++j) {
      int cl0 = 4 * iq + 16 * j;
      s16x4 ph;
#pragma unroll
      for (int mm = 0; mm < 4; ++mm) {
        const float* xp = xg + (size_t)(cl0 + mm) * 4096;
        float v = wt.x * xp[id.x] + wt.y * xp[id.y] + wt.z * xp[id.z] +
                  wt.w * xp[id.w];
        ph[mm] = (short)bfr(v);
      }
      *(s16x4*)&p_s[px * 68 + cl0] = ph;
    }
    __syncthreads();
#pragma unroll
    for (int s = 0; s < 2; ++s) {
      int k0 = 32 * s + quad * 8;
      s16x8 bf_f = ld8(&p_s[(16 * wv + l15) * 68 + k0]);
      const short* whb = wd_a + (size_t)g * 36864 + c * 64 + k0;
#pragma unroll
      for (int mt = 0; mt < 4; ++mt) {
        s16x8 af = *(const s16x8*)(whb + (size_t)(16 * mt + l15) * 576);
        acc[mt] = __builtin_amdgcn_mfma_f32_16x16x32_bf16(af, bf_f, acc[mt], 0, 0, 0);
      }
    }
    __syncthreads();
  }

  int nb = 16 * wv + l15;
#pragma unroll
  for (int mt = 0; mt < 4; ++mt) {
#pragma unroll
    for (int r = 0; r < 4; ++r) {
      int co = 16 * mt + quad * 4 + r;
      dcn[(((size_t)b * 256 + g * 64 + co) * 64 + h) * 64 + nb] =
          acc[mt][r] + b_dcn[g * 64 + co];
    }
  }
}

// LayerNorm over C + sigmoid + gate. dcn == out (in-place safe: each element
// is read only by its owning thread, and written after its final read).
__global__ __launch_bounds__(256) void k_ln(
    const float* __restrict__ dcn, const float* __restrict__ x,
    const float* __restrict__ gamma, const float* __restrict__ beta,
    float* __restrict__ out) {
  __shared__ float red_s[4][64];
  __shared__ float red_q[4][64];
  int px = threadIdx.x & 63;
  int part = threadIdx.x >> 6;
  int p = blockIdx.x * 64 + px;  // 32768 pixels
  int b = p >> 12, hw = p & 4095;
  const float* ob = dcn + (size_t)b * 256 * 4096 + hw;
  const float* xb = x + (size_t)b * 256 * 4096 + hw;
  float* yb = out + (size_t)b * 256 * 4096 + hw;
  int c0 = part * 64;
  float s = 0.f, s2 = 0.f;
  for (int c = c0; c < c0 + 64; ++c) {
    float v = ob[c * 4096];
    s += v;
    s2 += v * v;
  }
  red_s[part][px] = s;
  red_q[part][px] = s2;
  __syncthreads();
  s = red_s[0][px] + red_s[1][px] + red_s[2][px] + red_s[3][px];
  s2 = red_q[0][px] + red_q[1][px] + red_q[2][px] + red_q[3][px];
  float mu = s * (1.f / 256.f);
  float var = s2 * (1.f / 256.f) - mu * mu;
  float rs = rsqrtf(var + 1e-5f);
  for (int c = c0; c < c0 + 64; ++c) {
    float v = ob[c * 4096];
    float nrm = (v - mu) * rs * gamma[c] + beta[c];
    float attn = 1.f / (1.f + __expf(-nrm));
    yb[c * 4096] = xb[c * 4096] * attn;
  }
}

extern "C" void kernel_launch(void* const* d_in, const int* in_sizes, int n_in,
                              void* d_out, int out_size, void* d_ws,
                              size_t ws_size, hipStream_t stream) {
  const float* x = (const float*)d_in[0];
  const float* w_off = (const float*)d_in[1];
  const float* b_off = (const float*)d_in[2];
  const float* w_dcn = (const float*)d_in[3];
  const float* b_dcn = (const float*)d_in[4];
  const float* gamma = (const float*)d_in[5];
  const float* beta = (const float*)d_in[6];
  float* out = (float*)d_out;
  char* wsb = (char*)d_ws;

  short* wpart = (short*)wsb;                  // 28,311,552 B
  short* wo_a = (short*)(wsb + 28311552);      // 516,096 B
  short* wd_a = (short*)(wsb + 28827648);      // 294,912 B
  float* dcnb = out;                            // d_out doubles as dcn scratch

  k_prep<<<1584, 256, 0, stream>>>(w_off, w_dcn, wo_a, wd_a);
  k_offconv<<<2048, 256, 0, stream>>>(x, wo_a, b_off, wpart);
  k_dcn<<<2048, 256, 0, stream>>>(x, wpart, wd_a, b_dcn, dcnb);
  k_ln<<<512, 256, 0, stream>>>(dcnb, x, gamma, beta, out);
}

// Round 8
// 483.256 us; speedup vs baseline: 1.9352x; 1.0860x over previous
//
#include <hip/hip_runtime.h>
#include <math.h>

// B=8, C=256, H=W=64, G=4, K=3, KK=9, Cg=64
// Round 8: XCD-locality swizzle round (single change vs round 7).
//  Both hot kernels decode blockIdx so that xcd = bi&7 pins 4 x-slices
//  (4 MB = one XCD's L2) per XCD; the 64 h-blocks sharing a slice are
//  co-resident on that XCD -> gather/stage reads become L2 hits.
// ws layout (bytes):
//   wpart bf16 [4][8][108][4096] @ 0          (28,311,552)
//   wo_a  bf16 [112][2304]       @ 28,311,552 (516,096)   k = tap*256+ch
//   wd_a  bf16 [4][64][576]      @ 28,827,648 (294,912)   k = tap*64+cl
// total 29,122,560 B

typedef __attribute__((ext_vector_type(4))) short s16x4;
typedef __attribute__((ext_vector_type(8))) short s16x8;
typedef __attribute__((ext_vector_type(4))) float f32x4;

union S8 { s16x8 v; s16x4 h[2]; };

__device__ __forceinline__ s16x8 ld8(const short* p) {
  S8 r;
  r.h[0] = *(const s16x4*)p;
  r.h[1] = *(const s16x4*)(p + 4);
  return r.v;
}

__device__ __forceinline__ unsigned short bfr(float v) {  // RNE to bf16
  unsigned u = __float_as_uint(v);
  u = (u + 0x7FFFu + ((u >> 16) & 1u)) >> 16;
  return (unsigned short)u;
}
__device__ __forceinline__ float bff(unsigned short s) {
  return __uint_as_float(((unsigned)s) << 16);
}

__global__ __launch_bounds__(256) void k_prep(
    const float* __restrict__ w_off, const float* __restrict__ w_dcn,
    short* __restrict__ wo_a, short* __restrict__ wd_a) {
  int i = blockIdx.x * 256 + threadIdx.x;
  const int n1 = 112 * 2304;
  if (i < n1) {
    int co = i / 2304, k = i % 2304;
    int tap = k >> 8, ch = k & 255;  // k = tap*256 + ch
    float v = (co < 108) ? w_off[(co * 256 + ch) * 9 + tap] : 0.f;
    wo_a[i] = (short)bfr(v);
  } else {
    int j = i - n1;  // exactly 147456 remaining threads (grid 1584*256)
    int g = j / 36864, r = j % 36864;
    int co = r / 576, k = r % 576;
    int kk = k >> 6, cl = k & 63;  // k = tap*64 + cl
    wd_a[j] = (short)bfr(w_dcn[((g * 64 + co) * 64 + cl) * 9 + kk]);
  }
}

// Offset conv, bf16 MFMA, K-split by channel-quarter, XCD-pinned slices.
// slice = part*8+b (32 slices of 1 MB); xcd = bi&7 hosts slices xcd*4..xcd*4+3.
__global__ __launch_bounds__(256) void k_offconv(
    const float* __restrict__ x, const short* __restrict__ wo_a,
    const float* __restrict__ b_off, short* __restrict__ wpart) {
  __shared__ short p_s[64 * 68];
  int bi = blockIdx.x;  // 2048
  int xcd = bi & 7;
  int j = bi >> 3;
  int slice = xcd * 4 + (j & 3);  // 0..31, pinned to xcd
  int h = j >> 2;                 // 0..63
  int part = slice >> 3, b = slice & 7;
  int tid = threadIdx.x;
  int px = tid & 63, iq = tid >> 6;
  int lane = tid & 63, wv = tid >> 6;
  int quad = lane >> 4, l15 = lane & 15;

  f32x4 zero4 = {0.f, 0.f, 0.f, 0.f};
  f32x4 acc[7];
#pragma unroll
  for (int i = 0; i < 7; ++i) acc[i] = zero4;

  const float* xb = x + ((size_t)b * 256 + part * 64) * 4096;

  for (int tap = 0; tap < 9; ++tap) {
    int ky = tap / 3, kx = tap % 3;
    int hh = h - 1 + ky;
    int col = px - 1 + kx;
    bool vok = ((unsigned)hh < 64u) & ((unsigned)col < 64u);
    const float* xrow = xb + hh * 64 + col;
#pragma unroll
    for (int jj = 0; jj < 4; ++jj) {
      int cl0 = 4 * iq + 16 * jj;
      s16x4 ph;
#pragma unroll
      for (int m = 0; m < 4; ++m) {
        float v = vok ? xrow[(size_t)(cl0 + m) * 4096] : 0.f;
        ph[m] = (short)bfr(v);
      }
      *(s16x4*)&p_s[px * 68 + cl0] = ph;
    }
    __syncthreads();
#pragma unroll
    for (int s = 0; s < 2; ++s) {
      int k0 = 32 * s + quad * 8;
      s16x8 bf_f = ld8(&p_s[(16 * wv + l15) * 68 + k0]);
      const short* wb = wo_a + tap * 256 + part * 64 + k0;
#pragma unroll
      for (int mt = 0; mt < 7; ++mt) {
        s16x8 af = *(const s16x8*)(wb + (size_t)(16 * mt + l15) * 2304);
        acc[mt] = __builtin_amdgcn_mfma_f32_16x16x32_bf16(af, bf_f, acc[mt], 0, 0, 0);
      }
    }
    __syncthreads();
  }

  int nb = 16 * wv + l15;
  short* wp = wpart + ((size_t)part * 8 + b) * 108 * 4096;
#pragma unroll
  for (int mt = 0; mt < 7; ++mt) {
#pragma unroll
    for (int r = 0; r < 4; ++r) {
      int co = 16 * mt + quad * 4 + r;
      if (co < 108) {
        float v = acc[mt][r] + (part == 0 ? b_off[co] : 0.f);
        wp[(size_t)co * 4096 + h * 64 + nb] = (short)bfr(v);
      }
    }
  }
}

// DCN, bf16 MFMA, round-7 proven structure + XCD-pinned (b,g) groups.
// group = b*4+g (32 groups of 1 MB x-slice); xcd = bi&7 hosts groups xcd*4..+3.
__global__ __launch_bounds__(256) void k_dcn(
    const float* __restrict__ x, const short* __restrict__ wpart,
    const short* __restrict__ wd_a, const float* __restrict__ b_dcn,
    float* __restrict__ dcn) {
  __shared__ short p_s[64 * 68];

  int bi = blockIdx.x;  // 2048
  int xcd = bi & 7;
  int j = bi >> 3;
  int grp = xcd * 4 + (j & 3);  // 0..31, pinned to xcd
  int h = j >> 2;               // 0..63
  int b = grp >> 2, g = grp & 3;
  int tid = threadIdx.x;
  int px = tid & 63, iq = tid >> 6;
  int lane = tid & 63, wv = tid >> 6;
  int quad = lane >> 4, l15 = lane & 15;

  f32x4 zero4 = {0.f, 0.f, 0.f, 0.f};
  f32x4 acc[4];
#pragma unroll
  for (int i = 0; i < 4; ++i) acc[i] = zero4;

  const float* xg = x + ((size_t)b * 256 + g * 64) * 4096;
  int sp = h * 64 + px;

  for (int c = 0; c < 9; ++c) {
    // offset/mask params for (tap c, column px): fold 4 bf16 partials
    int co_y = (g * 9 + c) * 2;
    float oy = 0.f, ox = 0.f, mz = 0.f;
#pragma unroll
    for (int p4 = 0; p4 < 4; ++p4) {
      const short* wp = wpart + ((size_t)p4 * 8 + b) * 108 * 4096;
      oy += bff((unsigned short)wp[(size_t)co_y * 4096 + sp]);
      ox += bff((unsigned short)wp[(size_t)(co_y + 1) * 4096 + sp]);
      mz += bff((unsigned short)wp[(size_t)(72 + g * 9 + c) * 4096 + sp]);
    }
    float m = 1.f / (1.f + __expf(-mz));
    float py = (float)h + (float)(c / 3 - 1) + oy;
    float pxf = (float)px + (float)(c % 3 - 1) + ox;
    float y0 = floorf(py), x0 = floorf(pxf);
    float wy1 = py - y0, wy0 = 1.f - wy1;
    float wx1 = pxf - x0, wx0 = 1.f - wx1;
    int y0i = (int)y0, x0i = (int)x0;
    int y1i = y0i + 1, x1i = x0i + 1;
    bool vy0 = (y0i >= 0) & (y0i < 64), vy1 = (y1i >= 0) & (y1i < 64);
    bool vx0 = (x0i >= 0) & (x0i < 64), vx1 = (x1i >= 0) & (x1i < 64);
    int cy0 = min(max(y0i, 0), 63), cy1 = min(max(y1i, 0), 63);
    int cx0 = min(max(x0i, 0), 63), cx1 = min(max(x1i, 0), 63);
    int4 id = make_int4(cy0 * 64 + cx0, cy0 * 64 + cx1,
                        cy1 * 64 + cx0, cy1 * 64 + cx1);
    float4 wt = make_float4((vy0 && vx0) ? wy0 * wx0 * m : 0.f,
                            (vy0 && vx1) ? wy0 * wx1 * m : 0.f,
                            (vy1 && vx0) ? wy1 * wx0 * m : 0.f,
                            (vy1 && vx1) ? wy1 * wx1 * m : 0.f);
#pragma unroll
    for (int jj = 0; jj < 4; ++jj) {
      int cl0 = 4 * iq + 16 * jj;
      s16x4 ph;
#pragma unroll
      for (int mm = 0; mm < 4; ++mm) {
        const float* xp = xg + (size_t)(cl0 + mm) * 4096;
        float v = wt.x * xp[id.x] + wt.y * xp[id.y] + wt.z * xp[id.z] +
                  wt.w * xp[id.w];
        ph[mm] = (short)bfr(v);
      }
      *(s16x4*)&p_s[px * 68 + cl0] = ph;
    }
    __syncthreads();
#pragma unroll
    for (int s = 0; s < 2; ++s) {
      int k0 = 32 * s + quad * 8;
      s16x8 bf_f = ld8(&p_s[(16 * wv + l15) * 68 + k0]);
      const short* whb = wd_a + (size_t)g * 36864 + c * 64 + k0;
#pragma unroll
      for (int mt = 0; mt < 4; ++mt) {
        s16x8 af = *(const s16x8*)(whb + (size_t)(16 * mt + l15) * 576);
        acc[mt] = __builtin_amdgcn_mfma_f32_16x16x32_bf16(af, bf_f, acc[mt], 0, 0, 0);
      }
    }
    __syncthreads();
  }

  int nb = 16 * wv + l15;
#pragma unroll
  for (int mt = 0; mt < 4; ++mt) {
#pragma unroll
    for (int r = 0; r < 4; ++r) {
      int co = 16 * mt + quad * 4 + r;
      dcn[(((size_t)b * 256 + g * 64 + co) * 64 + h) * 64 + nb] =
          acc[mt][r] + b_dcn[g * 64 + co];
    }
  }
}

// LayerNorm over C + sigmoid + gate. dcn == out (in-place safe).
__global__ __launch_bounds__(256) void k_ln(
    const float* __restrict__ dcn, const float* __restrict__ x,
    const float* __restrict__ gamma, const float* __restrict__ beta,
    float* __restrict__ out) {
  __shared__ float red_s[4][64];
  __shared__ float red_q[4][64];
  int px = threadIdx.x & 63;
  int part = threadIdx.x >> 6;
  int p = blockIdx.x * 64 + px;  // 32768 pixels
  int b = p >> 12, hw = p & 4095;
  const float* ob = dcn + (size_t)b * 256 * 4096 + hw;
  const float* xb = x + (size_t)b * 256 * 4096 + hw;
  float* yb = out + (size_t)b * 256 * 4096 + hw;
  int c0 = part * 64;
  float s = 0.f, s2 = 0.f;
  for (int c = c0; c < c0 + 64; ++c) {
    float v = ob[c * 4096];
    s += v;
    s2 += v * v;
  }
  red_s[part][px] = s;
  red_q[part][px] = s2;
  __syncthreads();
  s = red_s[0][px] + red_s[1][px] + red_s[2][px] + red_s[3][px];
  s2 = red_q[0][px] + red_q[1][px] + red_q[2][px] + red_q[3][px];
  float mu = s * (1.f / 256.f);
  float var = s2 * (1.f / 256.f) - mu * mu;
  float rs = rsqrtf(var + 1e-5f);
  for (int c = c0; c < c0 + 64; ++c) {
    float v = ob[c * 4096];
    float nrm = (v - mu) * rs * gamma[c] + beta[c];
    float attn = 1.f / (1.f + __expf(-nrm));
    yb[c * 4096] = xb[c * 4096] * attn;
  }
}

extern "C" void kernel_launch(void* const* d_in, const int* in_sizes, int n_in,
                              void* d_out, int out_size, void* d_ws,
                              size_t ws_size, hipStream_t stream) {
  const float* x = (const float*)d_in[0];
  const float* w_off = (const float*)d_in[1];
  const float* b_off = (const float*)d_in[2];
  const float* w_dcn = (const float*)d_in[3];
  const float* b_dcn = (const float*)d_in[4];
  const float* gamma = (const float*)d_in[5];
  const float* beta = (const float*)d_in[6];
  float* out = (float*)d_out;
  char* wsb = (char*)d_ws;

  short* wpart = (short*)wsb;              // 28,311,552 B
  short* wo_a = (short*)(wsb + 28311552);  // 516,096 B
  short* wd_a = (short*)(wsb + 28827648);  // 294,912 B
  float* dcnb = out;                       // d_out doubles as dcn scratch

  k_prep<<<1584, 256, 0, stream>>>(w_off, w_dcn, wo_a, wd_a);
  k_offconv<<<2048, 256, 0, stream>>>(x, wo_a, b_off, wpart);
  k_dcn<<<2048, 256, 0, stream>>>(x, wpart, wd_a, b_dcn, dcnb);
  k_ln<<<512, 256, 0, stream>>>(dcnb, x, gamma, beta, out);
}

// Round 9
// 342.059 us; speedup vs baseline: 2.7340x; 1.4128x over previous
//
#include <hip/hip_runtime.h>
#include <math.h>

// B=8, C=256, H=W=64, G=4, K=3, KK=9, Cg=64
// Round 9: channel-chunked bf16 x-repack round (vs round 8: gather/stage
// source changes only; MFMA loops, swizzle, epilogues identical).
//   x2 layout: [b][c2=c/8][(h+1)*66+(w+1)][c&7] bf16, zero halo ->
//     - dcn gather: 8x16B loads per thread-tap (was 64 scalar dwords)
//     - offconv staging: 2x16B coalesced loads, no cvt, no bounds branch
// ws layout (bytes):
//   wpart bf16 [4][8][108][4096] @ 0          (28,311,552)
//   wo_a  bf16 [112][2304]       @ 28,311,552 (516,096)   k = tap*256+ch
//   wd_a  bf16 [4][64][576]      @ 28,827,648 (294,912)   k = tap*64+cl
//   x2    bf16 [256][4356][8]    @ 29,122,560 (17,842,176)
// total 46,964,736 B (< proven 48.3 MB)

typedef __attribute__((ext_vector_type(4))) short s16x4;
typedef __attribute__((ext_vector_type(8))) short s16x8;
typedef __attribute__((ext_vector_type(4))) float f32x4;

union S8 { s16x8 v; s16x4 h[2]; };

__device__ __forceinline__ s16x8 ld8(const short* p) {
  S8 r;
  r.h[0] = *(const s16x4*)p;
  r.h[1] = *(const s16x4*)(p + 4);
  return r.v;
}

__device__ __forceinline__ unsigned short bfr(float v) {  // RNE to bf16
  unsigned u = __float_as_uint(v);
  u = (u + 0x7FFFu + ((u >> 16) & 1u)) >> 16;
  return (unsigned short)u;
}
__device__ __forceinline__ float bff(unsigned short s) {
  return __uint_as_float(((unsigned)s) << 16);
}
__device__ __forceinline__ float bf(short s) {
  return __uint_as_float(((unsigned)(unsigned short)s) << 16);
}

__global__ __launch_bounds__(256) void k_prep(
    const float* __restrict__ w_off, const float* __restrict__ w_dcn,
    short* __restrict__ wo_a, short* __restrict__ wd_a) {
  int i = blockIdx.x * 256 + threadIdx.x;
  const int n1 = 112 * 2304;
  if (i < n1) {
    int co = i / 2304, k = i % 2304;
    int tap = k >> 8, ch = k & 255;  // k = tap*256 + ch
    float v = (co < 108) ? w_off[(co * 256 + ch) * 9 + tap] : 0.f;
    wo_a[i] = (short)bfr(v);
  } else {
    int j = i - n1;  // exactly 147456 remaining threads (grid 1584*256)
    int g = j / 36864, r = j % 36864;
    int co = r / 576, k = r % 576;
    int kk = k >> 6, cl = k & 63;  // k = tap*64 + cl
    wd_a[j] = (short)bfr(w_dcn[((g * 64 + co) * 64 + cl) * 9 + kk]);
  }
}

// x -> chunked bf16 NHWC with zero halo.
// interior: thread = (b, c2, pixel); border: zero 16B slots.
__global__ __launch_bounds__(256) void k_x2(
    const float* __restrict__ x, short* __restrict__ x2) {
  int id = blockIdx.x * 256 + threadIdx.x;
  const int n1 = 8 * 32 * 4096;  // 1,048,576 interior items
  if (id < n1) {
    int pc = id & 4095;
    int c2 = (id >> 12) & 31;
    int b = id >> 17;
    int h = pc >> 6, w = pc & 63;
    const float* xp = x + ((size_t)(b * 256 + c2 * 8)) * 4096 + pc;
    short* o = x2 + ((size_t)(b * 32 + c2) * 4356 + (h + 1) * 66 + (w + 1)) * 8;
    s16x4 v0, v1;
#pragma unroll
    for (int i = 0; i < 4; ++i) {
      v0[i] = (short)bfr(xp[(size_t)i * 4096]);
      v1[i] = (short)bfr(xp[(size_t)(i + 4) * 4096]);
    }
    *(s16x4*)o = v0;
    *(s16x4*)(o + 4) = v1;
  } else {
    int j = id - n1;  // grid sized exactly: j < 256*260
    int plane = j / 260, r = j % 260;
    int h, w;
    if (r < 66) { h = 0; w = r; }
    else if (r < 132) { h = 65; w = r - 66; }
    else if (r < 196) { h = r - 131; w = 0; }
    else { h = r - 195; w = 65; }
    short* o = x2 + ((size_t)plane * 4356 + h * 66 + w) * 8;
    s16x4 z = {0, 0, 0, 0};
    *(s16x4*)o = z;
    *(s16x4*)(o + 4) = z;
  }
}

// Offset conv, bf16 MFMA, K-split by channel-quarter, XCD-pinned slices.
// Staging now from x2: 2x16B coalesced loads/thread-tap, no cvt, no bounds.
__global__ __launch_bounds__(256) void k_offconv(
    const short* __restrict__ x2, const short* __restrict__ wo_a,
    const float* __restrict__ b_off, short* __restrict__ wpart) {
  __shared__ short p_s[64 * 68];
  int bi = blockIdx.x;  // 2048
  int xcd = bi & 7;
  int j = bi >> 3;
  int slice = xcd * 4 + (j & 3);  // 0..31, pinned to xcd
  int h = j >> 2;                 // 0..63
  int part = slice >> 3, b = slice & 7;
  int tid = threadIdx.x;
  int px = tid & 63, iq = tid >> 6;
  int lane = tid & 63, wv = tid >> 6;
  int quad = lane >> 4, l15 = lane & 15;

  f32x4 zero4 = {0.f, 0.f, 0.f, 0.f};
  f32x4 acc[7];
#pragma unroll
  for (int i = 0; i < 7; ++i) acc[i] = zero4;

  // planes for this block's 64 channels: (b*32 + part*8 + cc), cc = iq*2+j
  const short* x2b = x2 + (size_t)(b * 32 + part * 8) * 34848;

  for (int tap = 0; tap < 9; ++tap) {
    int ky = tap / 3, kx = tap % 3;
    int pix = (h + ky) * 66 + px + kx;  // padded coords: (h-1+ky+1, px-1+kx+1)
#pragma unroll
    for (int jj = 0; jj < 2; ++jj) {
      int cc = iq * 2 + jj;
      const short* pl = x2b + (size_t)cc * 34848 + (size_t)pix * 8;
      s16x4 v0 = *(const s16x4*)pl;
      s16x4 v1 = *(const s16x4*)(pl + 4);
      *(s16x4*)&p_s[px * 68 + iq * 16 + jj * 8] = v0;
      *(s16x4*)&p_s[px * 68 + iq * 16 + jj * 8 + 4] = v1;
    }
    __syncthreads();
#pragma unroll
    for (int s = 0; s < 2; ++s) {
      int k0 = 32 * s + quad * 8;
      s16x8 bf_f = ld8(&p_s[(16 * wv + l15) * 68 + k0]);
      const short* wb = wo_a + tap * 256 + part * 64 + k0;
#pragma unroll
      for (int mt = 0; mt < 7; ++mt) {
        s16x8 af = *(const s16x8*)(wb + (size_t)(16 * mt + l15) * 2304);
        acc[mt] = __builtin_amdgcn_mfma_f32_16x16x32_bf16(af, bf_f, acc[mt], 0, 0, 0);
      }
    }
    __syncthreads();
  }

  int nb = 16 * wv + l15;
  short* wp = wpart + ((size_t)part * 8 + b) * 108 * 4096;
#pragma unroll
  for (int mt = 0; mt < 7; ++mt) {
#pragma unroll
    for (int r = 0; r < 4; ++r) {
      int co = 16 * mt + quad * 4 + r;
      if (co < 108) {
        float v = acc[mt][r] + (part == 0 ? b_off[co] : 0.f);
        wp[(size_t)co * 4096 + h * 64 + nb] = (short)bfr(v);
      }
    }
  }
}

// DCN, bf16 MFMA, XCD-pinned (b,g) groups. Gather from x2: per thread-tap
// 4 corners x 2 chunks x 16B vector loads; bilinear combine in f32.
__global__ __launch_bounds__(256) void k_dcn(
    const short* __restrict__ x2, const short* __restrict__ wpart,
    const short* __restrict__ wd_a, const float* __restrict__ b_dcn,
    float* __restrict__ dcn) {
  __shared__ short p_s[64 * 68];

  int bi = blockIdx.x;  // 2048
  int xcd = bi & 7;
  int j = bi >> 3;
  int grp = xcd * 4 + (j & 3);  // 0..31, pinned to xcd
  int h = j >> 2;               // 0..63
  int b = grp >> 2, g = grp & 3;
  int tid = threadIdx.x;
  int px = tid & 63, iq = tid >> 6;
  int lane = tid & 63, wv = tid >> 6;
  int quad = lane >> 4, l15 = lane & 15;

  f32x4 zero4 = {0.f, 0.f, 0.f, 0.f};
  f32x4 acc[4];
#pragma unroll
  for (int i = 0; i < 4; ++i) acc[i] = zero4;

  const short* x2g = x2 + (size_t)(b * 32 + g * 8) * 34848;
  int sp = h * 64 + px;

  for (int c = 0; c < 9; ++c) {
    // offset/mask params for (tap c, column px): fold 4 bf16 partials
    int co_y = (g * 9 + c) * 2;
    float oy = 0.f, ox = 0.f, mz = 0.f;
#pragma unroll
    for (int p4 = 0; p4 < 4; ++p4) {
      const short* wp = wpart + ((size_t)p4 * 8 + b) * 108 * 4096;
      oy += bff((unsigned short)wp[(size_t)co_y * 4096 + sp]);
      ox += bff((unsigned short)wp[(size_t)(co_y + 1) * 4096 + sp]);
      mz += bff((unsigned short)wp[(size_t)(72 + g * 9 + c) * 4096 + sp]);
    }
    float m = 1.f / (1.f + __expf(-mz));
    float py = (float)h + (float)(c / 3 - 1) + oy;
    float pxf = (float)px + (float)(c % 3 - 1) + ox;
    float y0 = floorf(py), x0 = floorf(pxf);
    float wy1 = py - y0, wy0 = 1.f - wy1;
    float wx1 = pxf - x0, wx0 = 1.f - wx1;
    int y0i = (int)y0, x0i = (int)x0;
    int y1i = y0i + 1, x1i = x0i + 1;
    bool vy0 = (y0i >= 0) & (y0i < 64), vy1 = (y1i >= 0) & (y1i < 64);
    bool vx0 = (x0i >= 0) & (x0i < 64), vx1 = (x1i >= 0) & (x1i < 64);
    int cy0 = min(max(y0i, 0), 63) + 1, cy1 = min(max(y1i, 0), 63) + 1;
    int cx0 = min(max(x0i, 0), 63) + 1, cx1 = min(max(x1i, 0), 63) + 1;
    int4 id = make_int4(cy0 * 66 + cx0, cy0 * 66 + cx1,
                        cy1 * 66 + cx0, cy1 * 66 + cx1);
    float4 wt = make_float4((vy0 && vx0) ? wy0 * wx0 * m : 0.f,
                            (vy0 && vx1) ? wy0 * wx1 * m : 0.f,
                            (vy1 && vx0) ? wy1 * wx0 * m : 0.f,
                            (vy1 && vx1) ? wy1 * wx1 * m : 0.f);
#pragma unroll
    for (int jj = 0; jj < 2; ++jj) {
      int cc = iq * 2 + jj;
      const short* pl = x2g + (size_t)cc * 34848;
      s16x8 a00 = ld8(pl + (size_t)id.x * 8);
      s16x8 a01 = ld8(pl + (size_t)id.y * 8);
      s16x8 a10 = ld8(pl + (size_t)id.z * 8);
      s16x8 a11 = ld8(pl + (size_t)id.w * 8);
      s16x4 o0, o1;
#pragma unroll
      for (int i = 0; i < 8; ++i) {
        float v = wt.x * bf(a00[i]) + wt.y * bf(a01[i]) +
                  wt.z * bf(a10[i]) + wt.w * bf(a11[i]);
        if (i < 4) o0[i] = (short)bfr(v);
        else o1[i - 4] = (short)bfr(v);
      }
      *(s16x4*)&p_s[px * 68 + iq * 16 + jj * 8] = o0;
      *(s16x4*)&p_s[px * 68 + iq * 16 + jj * 8 + 4] = o1;
    }
    __syncthreads();
#pragma unroll
    for (int s = 0; s < 2; ++s) {
      int k0 = 32 * s + quad * 8;
      s16x8 bf_f = ld8(&p_s[(16 * wv + l15) * 68 + k0]);
      const short* whb = wd_a + (size_t)g * 36864 + c * 64 + k0;
#pragma unroll
      for (int mt = 0; mt < 4; ++mt) {
        s16x8 af = *(const s16x8*)(whb + (size_t)(16 * mt + l15) * 576);
        acc[mt] = __builtin_amdgcn_mfma_f32_16x16x32_bf16(af, bf_f, acc[mt], 0, 0, 0);
      }
    }
    __syncthreads();
  }

  int nb = 16 * wv + l15;
#pragma unroll
  for (int mt = 0; mt < 4; ++mt) {
#pragma unroll
    for (int r = 0; r < 4; ++r) {
      int co = 16 * mt + quad * 4 + r;
      dcn[(((size_t)b * 256 + g * 64 + co) * 64 + h) * 64 + nb] =
          acc[mt][r] + b_dcn[g * 64 + co];
    }
  }
}

// LayerNorm over C + sigmoid + gate. dcn == out (in-place safe).
__global__ __launch_bounds__(256) void k_ln(
    const float* __restrict__ dcn, const float* __restrict__ x,
    const float* __restrict__ gamma, const float* __restrict__ beta,
    float* __restrict__ out) {
  __shared__ float red_s[4][64];
  __shared__ float red_q[4][64];
  int px = threadIdx.x & 63;
  int part = threadIdx.x >> 6;
  int p = blockIdx.x * 64 + px;  // 32768 pixels
  int b = p >> 12, hw = p & 4095;
  const float* ob = dcn + (size_t)b * 256 * 4096 + hw;
  const float* xb = x + (size_t)b * 256 * 4096 + hw;
  float* yb = out + (size_t)b * 256 * 4096 + hw;
  int c0 = part * 64;
  float s = 0.f, s2 = 0.f;
  for (int c = c0; c < c0 + 64; ++c) {
    float v = ob[c * 4096];
    s += v;
    s2 += v * v;
  }
  red_s[part][px] = s;
  red_q[part][px] = s2;
  __syncthreads();
  s = red_s[0][px] + red_s[1][px] + red_s[2][px] + red_s[3][px];
  s2 = red_q[0][px] + red_q[1][px] + red_q[2][px] + red_q[3][px];
  float mu = s * (1.f / 256.f);
  float var = s2 * (1.f / 256.f) - mu * mu;
  float rs = rsqrtf(var + 1e-5f);
  for (int c = c0; c < c0 + 64; ++c) {
    float v = ob[c * 4096];
    float nrm = (v - mu) * rs * gamma[c] + beta[c];
    float attn = 1.f / (1.f + __expf(-nrm));
    yb[c * 4096] = xb[c * 4096] * attn;
  }
}

extern "C" void kernel_launch(void* const* d_in, const int* in_sizes, int n_in,
                              void* d_out, int out_size, void* d_ws,
                              size_t ws_size, hipStream_t stream) {
  const float* x = (const float*)d_in[0];
  const float* w_off = (const float*)d_in[1];
  const float* b_off = (const float*)d_in[2];
  const float* w_dcn = (const float*)d_in[3];
  const float* b_dcn = (const float*)d_in[4];
  const float* gamma = (const float*)d_in[5];
  const float* beta = (const float*)d_in[6];
  float* out = (float*)d_out;
  char* wsb = (char*)d_ws;

  short* wpart = (short*)wsb;              // 28,311,552 B
  short* wo_a = (short*)(wsb + 28311552);  // 516,096 B
  short* wd_a = (short*)(wsb + 28827648);  // 294,912 B
  short* x2 = (short*)(wsb + 29122560);    // 17,842,176 B
  float* dcnb = out;                       // d_out doubles as dcn scratch

  k_prep<<<1584, 256, 0, stream>>>(w_off, w_dcn, wo_a, wd_a);
  k_x2<<<4356, 256, 0, stream>>>(x, x2);
  k_offconv<<<2048, 256, 0, stream>>>(x2, wo_a, b_off, wpart);
  k_dcn<<<2048, 256, 0, stream>>>(x2, wpart, wd_a, b_dcn, dcnb);
  k_ln<<<512, 256, 0, stream>>>(dcnb, x, gamma, beta, out);
}